// Round 1
// baseline (115.374 us; speedup 1.0000x reference)
//
#include <hip/hip_runtime.h>

#define NN 2048
#define DD 128
#define HH 64

// ---------------- Kernel 1: projections ----------------
// pi[i][h]  = agent[i] . W1a[:,h]
// pjt[j][h] = agent[j] . W1b[:,h] + (task . W1c[:,h] + b1[h])
// 128 blocks x 256 threads; each block does 16 rows, each thread 4 rows x 1 h.
__global__ __launch_bounds__(256) void proj_kernel(
    const float* __restrict__ z, const float* __restrict__ W1,
    const float* __restrict__ b1, float* __restrict__ pi, float* __restrict__ pjt)
{
    __shared__ float sA[16][DD];
    __shared__ float sT[DD];
    const int t = threadIdx.x;
    const int rowBase = blockIdx.x * 16;

    // stage 16 agent rows: 16*128 floats = 512 float4s, 2 per thread (coalesced)
    #pragma unroll
    for (int c = 0; c < 2; ++c) {
        int idx = c * 256 + t;          // float4 index 0..511
        int rr  = idx >> 5;             // 32 float4 per row
        int kq  = idx & 31;
        float4 v = *(const float4*)(z + (rowBase + rr) * DD + kq * 4);
        *(float4*)(&sA[rr][kq * 4]) = v;
    }
    if (t < DD / 4) {
        float4 v = *(const float4*)(z + (size_t)NN * DD + t * 4);  // task row
        *(float4*)(&sT[t * 4]) = v;
    }
    __syncthreads();

    const int h  = t & 63;
    const int rg = t >> 6;              // wave-uniform -> sA reads broadcast

    float ai[4] = {0.f, 0.f, 0.f, 0.f};
    float aj[4] = {0.f, 0.f, 0.f, 0.f};
    float at = 0.f;
    #pragma unroll 4
    for (int k = 0; k < DD; ++k) {
        const float w1a = W1[k * HH + h];              // coalesced, L2-resident
        const float w1b = W1[(DD + k) * HH + h];
        const float w1c = W1[(2 * DD + k) * HH + h];
        at = fmaf(sT[k], w1c, at);
        #pragma unroll
        for (int a = 0; a < 4; ++a) {
            const float av = sA[rg * 4 + a][k];
            ai[a] = fmaf(av, w1a, ai[a]);
            aj[a] = fmaf(av, w1b, aj[a]);
        }
    }
    const float ptv = at + b1[h];
    #pragma unroll
    for (int a = 0; a < 4; ++a) {
        const int row = rowBase + rg * 4 + a;
        pi[row * HH + h]  = ai[a];
        pjt[row * HH + h] = aj[a] + ptv;
    }
}

// ---------------- Kernel 2: pairwise decode ----------------
// out[i][j] = e / (e + (1-e)*exp(-w)),  w = sum_h relu(pi[i][h]+pjt[j][h])*W2[h] + b2
// grid (32,32); block 256 = 4 waves; block tile 64x64; wave tile 32x32; thread 4x4.
// LDS tiles transposed [h][i] with stride 68: per-h ds_read_b128 of 4 i's has 8
// distinct 16B addresses/wave covering all 32 banks -> conflict-free + broadcast.
__global__ __launch_bounds__(256) void pair_kernel(
    const float* __restrict__ pi, const float* __restrict__ pjt,
    const float* __restrict__ W2, const float* __restrict__ b2,
    const float* __restrict__ eps, float* __restrict__ out)
{
    __shared__ float sPi[HH][68];
    __shared__ float sPj[HH][68];
    __shared__ float sW2[HH];

    const int t  = threadIdx.x;
    const int i0 = blockIdx.y * 64;
    const int j0 = blockIdx.x * 64;

    // stage: 64 rows x 64 h of each of pi/pjt, transposing into [h][i]
    #pragma unroll
    for (int c = 0; c < 4; ++c) {
        int idx = c * 256 + t;          // float4 index 0..1023
        int ii  = idx >> 4;             // 0..63 (row in tile)
        int hq  = idx & 15;             // h quad
        float4 v = *(const float4*)(pi  + (size_t)(i0 + ii) * HH + hq * 4);
        sPi[hq * 4 + 0][ii] = v.x;
        sPi[hq * 4 + 1][ii] = v.y;
        sPi[hq * 4 + 2][ii] = v.z;
        sPi[hq * 4 + 3][ii] = v.w;
        float4 u = *(const float4*)(pjt + (size_t)(j0 + ii) * HH + hq * 4);
        sPj[hq * 4 + 0][ii] = u.x;
        sPj[hq * 4 + 1][ii] = u.y;
        sPj[hq * 4 + 2][ii] = u.z;
        sPj[hq * 4 + 3][ii] = u.w;
    }
    if (t < HH) sW2[t] = W2[t];
    __syncthreads();

    const int lane = t & 63;
    const int wv   = t >> 6;
    const int iloc = (wv & 1) * 32 + (lane & 7) * 4;   // 8 i-groups per wave
    const int jloc = (wv >> 1) * 32 + (lane >> 3) * 4; // 8 j-groups per wave

    float acc[4][4];
    #pragma unroll
    for (int a = 0; a < 4; ++a)
        #pragma unroll
        for (int b = 0; b < 4; ++b) acc[a][b] = 0.f;

    #pragma unroll 8
    for (int h = 0; h < HH; ++h) {
        const float4 av = *(const float4*)(&sPi[h][iloc]);
        const float4 bv = *(const float4*)(&sPj[h][jloc]);
        const float w2h = sW2[h];
        const float a4[4] = {av.x, av.y, av.z, av.w};
        const float b4[4] = {bv.x, bv.y, bv.z, bv.w};
        #pragma unroll
        for (int a = 0; a < 4; ++a)
            #pragma unroll
            for (int b = 0; b < 4; ++b)
                acc[a][b] = fmaf(fmaxf(a4[a] + b4[b], 0.f), w2h, acc[a][b]);
    }

    const float b2v = b2[0];
    #pragma unroll
    for (int a = 0; a < 4; ++a) {
        const int gi = i0 + iloc + a;
        const size_t base = (size_t)gi * NN + j0 + jloc;
        const float4 e4 = *(const float4*)(eps + base);
        float4 o;
        {
            float e = e4.x + 1e-8f, w = acc[a][0] + b2v;
            float ex = __expf(-w);
            o.x = __fdividef(e, e + (1.f - e) * ex);
        }
        {
            float e = e4.y + 1e-8f, w = acc[a][1] + b2v;
            float ex = __expf(-w);
            o.y = __fdividef(e, e + (1.f - e) * ex);
        }
        {
            float e = e4.z + 1e-8f, w = acc[a][2] + b2v;
            float ex = __expf(-w);
            o.z = __fdividef(e, e + (1.f - e) * ex);
        }
        {
            float e = e4.w + 1e-8f, w = acc[a][3] + b2v;
            float ex = __expf(-w);
            o.w = __fdividef(e, e + (1.f - e) * ex);
        }
        *(float4*)(out + base) = o;
    }
}

extern "C" void kernel_launch(void* const* d_in, const int* in_sizes, int n_in,
                              void* d_out, int out_size, void* d_ws, size_t ws_size,
                              hipStream_t stream) {
    const float* z   = (const float*)d_in[0];   // (2049,128)
    const float* W1  = (const float*)d_in[1];   // (384,64)
    const float* b1  = (const float*)d_in[2];   // (64,)
    const float* W2  = (const float*)d_in[3];   // (64,1)
    const float* b2  = (const float*)d_in[4];   // (1,)
    const float* eps = (const float*)d_in[5];   // (2048,2048)
    float* out = (float*)d_out;                 // (2048,2048) fp32

    float* pi  = (float*)d_ws;                  // N*H floats
    float* pjt = pi + (size_t)NN * HH;          // N*H floats (total 1 MB)

    proj_kernel<<<NN / 16, 256, 0, stream>>>(z, W1, b1, pi, pjt);
    pair_kernel<<<dim3(NN / 64, NN / 64), 256, 0, stream>>>(pi, pjt, W2, b2, eps, out);
}